// Round 7
// baseline (348.873 us; speedup 1.0000x reference)
//
#include <hip/hip_runtime.h>

#define NN 2048
#define DD 128

typedef _Float16 f16x8 __attribute__((ext_vector_type(8)));
typedef float f32x4 __attribute__((ext_vector_type(4)));

// ---------------------------------------------------------------------------
// prep: Wt[l][d][k] = fp16(W[l][k][d])
// ---------------------------------------------------------------------------
__global__ __launch_bounds__(256) void prep_kernel(
    const float* __restrict__ W, _Float16* __restrict__ Wt) {
  int idx = blockIdx.x * 256 + threadIdx.x;
  int l = idx >> 14, r = idx & 16383, d = r >> 7, k = r & 127;
  Wt[idx] = (_Float16)W[l * 16384 + k * 128 + d];
}

// ---------------------------------------------------------------------------
// gemmY (layer 0 only): Yt[b][d][n] = sum_k x0[b][n][k] * W0[k][d]
// LDS-free, barrier-free.
// ---------------------------------------------------------------------------
__global__ __launch_bounds__(256) void gemmY_kernel(
    const float* __restrict__ X, const _Float16* __restrict__ Wt,
    _Float16* __restrict__ Yt) {
  const int bx = blockIdx.x;
  const int batch = bx & 7, n0 = (bx >> 3) * 32;
  const int tid = threadIdx.x, lane = tid & 63, wave = tid >> 6;
  const int quad = lane >> 4, l15 = lane & 15, d0 = wave * 32;
  f32x4 acc[2][2] = {};
#pragma unroll
  for (int kk = 0; kk < 128; kk += 32) {
    f16x8 a0 = *(const f16x8*)(Wt + (d0 + l15) * DD + kk + quad * 8);
    f16x8 a1 = *(const f16x8*)(Wt + (d0 + 16 + l15) * DD + kk + quad * 8);
#pragma unroll
    for (int fi = 0; fi < 2; ++fi) {
      const float* xp = X + (size_t)(batch * NN + n0 + fi * 16 + l15) * DD + kk + quad * 8;
      float4 x0 = *(const float4*)xp;
      float4 x1 = *(const float4*)(xp + 4);
      f16x8 b = {(_Float16)x0.x, (_Float16)x0.y, (_Float16)x0.z, (_Float16)x0.w,
                 (_Float16)x1.x, (_Float16)x1.y, (_Float16)x1.z, (_Float16)x1.w};
      acc[0][fi] = __builtin_amdgcn_mfma_f32_16x16x32_f16(a0, b, acc[0][fi], 0, 0, 0);
      acc[1][fi] = __builtin_amdgcn_mfma_f32_16x16x32_f16(a1, b, acc[1][fi], 0, 0, 0);
    }
  }
  _Float16* YtB = Yt + (size_t)batch * DD * NN;
#pragma unroll
  for (int df = 0; df < 2; ++df)
#pragma unroll
    for (int fi = 0; fi < 2; ++fi)
#pragma unroll
      for (int r = 0; r < 4; ++r)
        YtB[(size_t)(d0 + df * 16 + quad * 4 + r) * NN + n0 + fi * 16 + l15] =
            (_Float16)acc[df][fi][r];
}

// ---------------------------------------------------------------------------
// agg: Z[i][d] = sum_j adj[i][j]*Yt[d][j]; act = relu((Z+b)/(rowsum+1))
// ZERO barriers / ZERO LDS in the j-loop. A-operand = adj rows (fp32 loads,
// packed cvt in regs), B-operand = Yt rows (f16x8, XCD-L2-resident).
// Wave = 32 i x 128 d (acc 64 VGPR). ONE wave per block, 512 blocks
// (= 2 waves/CU), depth-4 rotating register pipeline (48 loads in flight).
// __launch_bounds__(64,1) -> VGPR cap 512: no spill (round-5 lesson).
// Epilogue: rowsum via shfl, bias+relu; !LAST fuses the next layer's Linear
// through a per-wave LDS transpose (activations never touch HBM).
// ---------------------------------------------------------------------------
template<bool LAST>
__global__ __launch_bounds__(64, 1) void agg_kernel(
    const float* __restrict__ adj, const _Float16* __restrict__ Yt,
    const float* __restrict__ bias, const _Float16* __restrict__ Wn,
    _Float16* __restrict__ Ytn, float* __restrict__ out) {
  __shared__ _Float16 acts[32][136];
  __shared__ float rd[32];

  const int bx = blockIdx.x;
  const int batch = bx & 7, i0 = (bx >> 3) * 32;
  const int lane = threadIdx.x & 63;
  const int quad = lane >> 4, l15 = lane & 15;

  const float* A0p = adj + (size_t)(batch * NN + i0 + l15) * NN + quad * 8;
  const float* A1p = A0p + (size_t)16 * NN;
  const _Float16* Yb = Yt + (size_t)batch * DD * NN + (size_t)l15 * NN + quad * 8;

  f32x4 acc[2][8] = {};
  float rs0 = 0.f, rs1 = 0.f;

  float4 pa[4][4];     // rotating stages: adj (2 i-frags x 2 float4)
  f16x8 py[4][8];      // rotating stages: Yt  (8 d-frags)

#define LOADS(jj, st)                                                   \
  do {                                                                  \
    pa[st][0] = *(const float4*)(A0p + (jj));                           \
    pa[st][1] = *(const float4*)(A0p + (jj) + 4);                       \
    pa[st][2] = *(const float4*)(A1p + (jj));                           \
    pa[st][3] = *(const float4*)(A1p + (jj) + 4);                       \
    _Pragma("unroll")                                                   \
    for (int f = 0; f < 8; ++f)                                         \
      py[st][f] = *(const f16x8*)(Yb + (size_t)(f * 16) * NN + (jj));   \
  } while (0)

#define COMPUTE(st)                                                     \
  do {                                                                  \
    float4 a00 = pa[st][0], a01 = pa[st][1];                            \
    float4 a10 = pa[st][2], a11 = pa[st][3];                            \
    f16x8 y[8];                                                         \
    _Pragma("unroll")                                                   \
    for (int f = 0; f < 8; ++f) y[f] = py[st][f];                       \
    rs0 += ((a00.x + a00.y) + (a00.z + a00.w)) +                        \
           ((a01.x + a01.y) + (a01.z + a01.w));                         \
    rs1 += ((a10.x + a10.y) + (a10.z + a10.w)) +                        \
           ((a11.x + a11.y) + (a11.z + a11.w));                         \
    f16x8 af0 = {(_Float16)a00.x, (_Float16)a00.y, (_Float16)a00.z,     \
                 (_Float16)a00.w, (_Float16)a01.x, (_Float16)a01.y,     \
                 (_Float16)a01.z, (_Float16)a01.w};                     \
    f16x8 af1 = {(_Float16)a10.x, (_Float16)a10.y, (_Float16)a10.z,     \
                 (_Float16)a10.w, (_Float16)a11.x, (_Float16)a11.y,     \
                 (_Float16)a11.z, (_Float16)a11.w};                     \
    _Pragma("unroll")                                                   \
    for (int f = 0; f < 8; ++f) {                                       \
      acc[0][f] = __builtin_amdgcn_mfma_f32_16x16x32_f16(af0, y[f], acc[0][f], 0, 0, 0); \
      acc[1][f] = __builtin_amdgcn_mfma_f32_16x16x32_f16(af1, y[f], acc[1][f], 0, 0, 0); \
    }                                                                   \
  } while (0)

  LOADS(0, 0); LOADS(32, 1); LOADS(64, 2); LOADS(96, 3);

  for (int j = 0; j < NN - 128; j += 128) {
#pragma unroll
    for (int u = 0; u < 4; ++u) {
      COMPUTE(u);
      LOADS(j + u * 32 + 128, u);   // refill stage u, consumed 4 steps later
    }
  }
#pragma unroll
  for (int u = 0; u < 4; ++u) COMPUTE(u);   // tail: stages hold j=1920..2047
#undef LOADS
#undef COMPUTE

  // full row sums: quads hold disjoint k-slices of the same row (l15)
  rs0 += __shfl_xor(rs0, 16); rs0 += __shfl_xor(rs0, 32);
  rs1 += __shfl_xor(rs1, 16); rs1 += __shfl_xor(rs1, 32);
  if (lane < 16) {
    rd[l15] = 1.0f / (rs0 + 1.0f);
    rd[16 + l15] = 1.0f / (rs1 + 1.0f);
  }
  __syncthreads();   // single-wave block: cheap

  float bv[8];
#pragma unroll
  for (int f = 0; f < 8; ++f) bv[f] = bias[f * 16 + l15];
  float rdv[2][4];
#pragma unroll
  for (int fi = 0; fi < 2; ++fi)
#pragma unroll
    for (int r = 0; r < 4; ++r) rdv[fi][r] = rd[fi * 16 + quad * 4 + r];

  if (LAST) {
    float* ob = out + (size_t)(batch * NN + i0) * DD;
#pragma unroll
    for (int fi = 0; fi < 2; ++fi)
#pragma unroll
      for (int f = 0; f < 8; ++f)
#pragma unroll
        for (int r = 0; r < 4; ++r) {
          int i = fi * 16 + quad * 4 + r;
          ob[(size_t)i * DD + f * 16 + l15] =
              fmaxf((acc[fi][f][r] + bv[f]) * rdv[fi][r], 0.f);
        }
  } else {
#pragma unroll
    for (int fi = 0; fi < 2; ++fi)
#pragma unroll
      for (int f = 0; f < 8; ++f)
#pragma unroll
        for (int r = 0; r < 4; ++r) {
          int i = fi * 16 + quad * 4 + r;
          acts[i][f * 16 + l15] =
              (_Float16)fmaxf((acc[fi][f][r] + bv[f]) * rdv[fi][r], 0.f);
        }
    __syncthreads();
    // fused next-layer Linear: Ytn[d2][i] = sum_d acts[i][d] * Wn_t[d2][d]
    f32x4 acc2[8][2] = {};
#pragma unroll
    for (int kk = 0; kk < 128; kk += 32) {
      f16x8 b0 = *(const f16x8*)&acts[l15][kk + quad * 8];
      f16x8 b1 = *(const f16x8*)&acts[16 + l15][kk + quad * 8];
#pragma unroll
      for (int m = 0; m < 8; ++m) {
        f16x8 aw = *(const f16x8*)(Wn + (m * 16 + l15) * DD + kk + quad * 8);
        acc2[m][0] = __builtin_amdgcn_mfma_f32_16x16x32_f16(aw, b0, acc2[m][0], 0, 0, 0);
        acc2[m][1] = __builtin_amdgcn_mfma_f32_16x16x32_f16(aw, b1, acc2[m][1], 0, 0, 0);
      }
    }
    _Float16* Yn = Ytn + (size_t)batch * DD * NN;
#pragma unroll
    for (int m = 0; m < 8; ++m)
#pragma unroll
      for (int nf = 0; nf < 2; ++nf)
#pragma unroll
        for (int r = 0; r < 4; ++r)
          Yn[(size_t)(m * 16 + quad * 4 + r) * NN + i0 + nf * 16 + l15] =
              (_Float16)acc2[m][nf][r];
  }
}

extern "C" void kernel_launch(void* const* d_in, const int* in_sizes, int n_in,
                              void* d_out, int out_size, void* d_ws, size_t ws_size,
                              hipStream_t stream) {
  const float* x0   = (const float*)d_in[0];   // [8,2048,128]
  const float* adj  = (const float*)d_in[1];   // [8,2048,2048]
  const float* W    = (const float*)d_in[2];   // [3,128,128]
  const float* bias = (const float*)d_in[3];   // [3,128]
  float* out = (float*)d_out;

  char* ws = (char*)d_ws;
  _Float16* Wt  = (_Float16*)ws;                      // 96 KB fp16 W^T x3
  _Float16* Yt0 = (_Float16*)(ws + (1u << 20));       // 4 MB (reused as Yt2)
  _Float16* Yt1 = (_Float16*)(ws + 6u * (1u << 20));  // 4 MB

  prep_kernel <<<192, 256, 0, stream>>>(W, Wt);
  gemmY_kernel<<<512, 256, 0, stream>>>(x0, Wt, Yt0);
  // layer 1 agg (+ fused layer-2 Linear)
  agg_kernel<false><<<512, 64, 0, stream>>>(adj, Yt0, bias,       Wt + 16384, Yt1, nullptr);
  // layer 2 agg (+ fused layer-3 Linear)
  agg_kernel<false><<<512, 64, 0, stream>>>(adj, Yt1, bias + 128, Wt + 32768, Yt0, nullptr);
  // layer 3 agg -> final fp32 output
  agg_kernel<true ><<<512, 64, 0, stream>>>(adj, Yt0, bias + 256, nullptr,    nullptr, out);
}